// Round 9
// baseline (351.488 us; speedup 1.0000x reference)
//
#include <hip/hip_runtime.h>

#define BSHIFT 11
#define BSZ (1 << BSHIFT)          // 2048 nodes per bucket
#define NBMAX 512
#define NBIN_BLOCKS 1024           // histogram/placement chunks
#define PB 512                     // k_place2 threads
#define BATCH 8192                 // edges sorted per LDS batch

typedef int          int32x4  __attribute__((ext_vector_type(4)));
typedef unsigned int uint32x4 __attribute__((ext_vector_type(4)));
typedef unsigned int uint32x2 __attribute__((ext_vector_type(2)));

// ---------------- node-map kernels ----------------

__global__ void k1b(const float* __restrict__ feat, const float* __restrict__ norm,
                    float* __restrict__ g1, int n) {
    int stride = gridDim.x * blockDim.x;
    for (int i = blockIdx.x * blockDim.x + threadIdx.x; i < n; i += stride)
        g1[i] = feat[i] * norm[i];
}

// fallback path helpers
__global__ void k1_prep(const float* __restrict__ feat, const float* __restrict__ norm,
                        float* __restrict__ g1, float* __restrict__ agg1,
                        float* __restrict__ agg2, int n) {
    int stride = gridDim.x * blockDim.x;
    for (int i = blockIdx.x * blockDim.x + threadIdx.x; i < n; i += stride) {
        g1[i] = feat[i] * norm[i];
        agg1[i] = 0.0f;
        agg2[i] = 0.0f;
    }
}

__global__ void k3_mid(const float* __restrict__ agg1, const float* __restrict__ norm,
                       const float* __restrict__ W1, const float* __restrict__ b1,
                       const float* __restrict__ W2, float* __restrict__ t, int n) {
    float w10 = W1[0], w11 = W1[1], w12 = W1[2];
    float b10 = b1[0], b11 = b1[1], b12 = b1[2];
    float w20 = W2[0], w21 = W2[1], w22 = W2[2];
    int stride = gridDim.x * blockDim.x;
    for (int i = blockIdx.x * blockDim.x + threadIdx.x; i < n; i += stride) {
        float nv = norm[i];
        float s = agg1[i] * nv;
        float h0 = fmaxf(fmaf(s, w10, b10), 0.0f);
        float h1 = fmaxf(fmaf(s, w11, b11), 0.0f);
        float h2 = fmaxf(fmaf(s, w12, b12), 0.0f);
        t[i] = nv * (h0 * w20 + h1 * w21 + h2 * w22);
    }
}

__global__ void k5_out(const float* __restrict__ agg2, const float* __restrict__ norm,
                       const float* __restrict__ b2, float* __restrict__ out, int n) {
    float b = b2[0];
    int stride = gridDim.x * blockDim.x;
    for (int i = blockIdx.x * blockDim.x + threadIdx.x; i < n; i += stride)
        out[i] = fmaxf(agg2[i] * norm[i] + b, 0.0f);
}

// ---------------- binning pipeline ----------------

// H: per-chunk LDS histogram -> counts[b * NBIN_BLOCKS + chunk]  (transposed)
// Regular (cached) loads: dst is re-read by k_place2 and wants L2.
__global__ void k_hist(const int* __restrict__ dst, int nE, int NB, int chunk,
                       int* __restrict__ counts) {
    extern __shared__ int lhist[];
    int t = threadIdx.x;
    for (int b = t; b < NB; b += blockDim.x) lhist[b] = 0;
    __syncthreads();
    int lo = blockIdx.x * chunk;
    int hi = min(lo + chunk, nE);
    int n4 = (hi - lo) >> 2;                       // lo % 4 == 0 (chunk % 4 == 0)
    const int4* d4 = (const int4*)(dst + lo);
    for (int i = t; i < n4; i += blockDim.x) {
        int4 v = d4[i];
        atomicAdd(&lhist[v.x >> BSHIFT], 1);
        atomicAdd(&lhist[v.y >> BSHIFT], 1);
        atomicAdd(&lhist[v.z >> BSHIFT], 1);
        atomicAdd(&lhist[v.w >> BSHIFT], 1);
    }
    for (int i = lo + (n4 << 2) + t; i < hi; i += blockDim.x)
        atomicAdd(&lhist[dst[i] >> BSHIFT], 1);
    __syncthreads();
    for (int b = t; b < NB; b += blockDim.x)
        counts[(size_t)b * NBIN_BLOCKS + blockIdx.x] = lhist[b];
}

// S1: one block per bucket — exclusive scan of its 1024 chunk counts.
__global__ void k_bucketscan(const int* __restrict__ counts,
                             int* __restrict__ chunkpre, int* __restrict__ tot) {
    __shared__ int ssum[256];
    int b = blockIdx.x;
    int t = threadIdx.x;
    const int4* in4 = (const int4*)(counts + (size_t)b * NBIN_BLOCKS);
    int4 v = in4[t];
    int mysum = v.x + v.y + v.z + v.w;
    ssum[t] = mysum;
    __syncthreads();
    for (int ofs = 1; ofs < 256; ofs <<= 1) {
        int add = (t >= ofs) ? ssum[t - ofs] : 0;
        __syncthreads();
        ssum[t] += add;
        __syncthreads();
    }
    int excl = ssum[t] - mysum;
    int4 o;
    o.x = excl;
    o.y = excl + v.x;
    o.z = o.y + v.y;
    o.w = o.z + v.z;
    ((int4*)(chunkpre + (size_t)b * NBIN_BLOCKS))[t] = o;
    if (t == 255) tot[b] = ssum[255];
}

// S2: exclusive scan over NB bucket totals -> base[0..NB]
__global__ void k_exscan(const int* __restrict__ tot, int NB, int* __restrict__ base) {
    __shared__ int s[1024];
    int t = threadIdx.x;
    if (NB < 1024) {
        int v = (t < NB) ? tot[t] : 0;
        s[t] = v;
        __syncthreads();
        for (int ofs = 1; ofs < 1024; ofs <<= 1) {
            int add = (t >= ofs) ? s[t - ofs] : 0;
            __syncthreads();
            s[t] += add;
            __syncthreads();
        }
        if (t < NB) base[t] = s[t] - v;
        if (t == NB) base[NB] = s[NB - 1];
    } else if (t == 0) {
        int run = 0;
        for (int b = 0; b < NB; ++b) { base[b] = run; run += tot[b]; }
        base[NB] = run;
    }
}

// P2: LDS-sorted placement. IV=false: write packed u32. IV=true: gather g1 in
// the flush and write {pack, val} u32x2 records (pass-1 gather eliminated).
template <bool IV>
__global__ void __launch_bounds__(PB)
k_place2x(const int* __restrict__ src, const int* __restrict__ dst,
          const float* __restrict__ g1, int nE, int NB, int chunk,
          const int* __restrict__ chunkpre, const int* __restrict__ base,
          unsigned int* __restrict__ bpack, uint32x2* __restrict__ bpack2) {
    __shared__ unsigned int spack[BATCH];      // 32 KB sorted packed edges
    __shared__ unsigned short sbkt[BATCH];     // 16 KB bucket id per slot
    __shared__ int lcur[NBMAX];
    __shared__ int loff[NBMAX + 1];
    __shared__ int gcur[NBMAX];
    __shared__ int ssc[NBMAX];
    int t = threadIdx.x;
    int blk = blockIdx.x;

    for (int b = t; b < NB; b += PB)
        gcur[b] = base[b] + chunkpre[(size_t)b * NBIN_BLOCKS + blk];

    int lo = blk * chunk;
    int hi = min(lo + chunk, nE);
    for (int bs = lo; bs < hi; bs += BATCH) {
        int be = min(bs + BATCH, hi);
        int cnt = be - bs;
        lcur[t] = 0;
        __syncthreads();
        // phase A: batch histogram (cached int4 loads; bs % 4 == 0)
        int n4 = cnt >> 2;
        const int4* d4 = (const int4*)(dst + bs);
        for (int i = t; i < n4; i += PB) {
            int4 v = d4[i];
            atomicAdd(&lcur[v.x >> BSHIFT], 1);
            atomicAdd(&lcur[v.y >> BSHIFT], 1);
            atomicAdd(&lcur[v.z >> BSHIFT], 1);
            atomicAdd(&lcur[v.w >> BSHIFT], 1);
        }
        for (int i = bs + (n4 << 2) + t; i < be; i += PB)
            atomicAdd(&lcur[dst[i] >> BSHIFT], 1);
        __syncthreads();
        // scan 512 (Hillis-Steele inclusive) -> exclusive offsets
        int v = lcur[t];
        ssc[t] = v;
        __syncthreads();
        for (int ofs = 1; ofs < 512; ofs <<= 1) {
            int add = (t >= ofs) ? ssc[t - ofs] : 0;
            __syncthreads();
            ssc[t] += add;
            __syncthreads();
        }
        int excl = ssc[t] - v;
        loff[t] = excl;
        lcur[t] = excl;
        if (t == 511) loff[512] = ssc[511];
        __syncthreads();
        // phase B: sorted scatter into LDS (cached int4 loads; dst hits L2)
        const int4* s4 = (const int4*)(src + bs);
        for (int i = t; i < n4; i += PB) {
            int4 dv = d4[i];
            int4 sv = s4[i];
            int b0 = dv.x >> BSHIFT, p0 = atomicAdd(&lcur[b0], 1);
            spack[p0] = ((unsigned int)sv.x << BSHIFT) | (unsigned int)(dv.x & (BSZ - 1));
            sbkt[p0] = (unsigned short)b0;
            int b1 = dv.y >> BSHIFT, p1 = atomicAdd(&lcur[b1], 1);
            spack[p1] = ((unsigned int)sv.y << BSHIFT) | (unsigned int)(dv.y & (BSZ - 1));
            sbkt[p1] = (unsigned short)b1;
            int b2 = dv.z >> BSHIFT, p2 = atomicAdd(&lcur[b2], 1);
            spack[p2] = ((unsigned int)sv.z << BSHIFT) | (unsigned int)(dv.z & (BSZ - 1));
            sbkt[p2] = (unsigned short)b2;
            int b3 = dv.w >> BSHIFT, p3 = atomicAdd(&lcur[b3], 1);
            spack[p3] = ((unsigned int)sv.w << BSHIFT) | (unsigned int)(dv.w & (BSZ - 1));
            sbkt[p3] = (unsigned short)b3;
        }
        for (int i = bs + (n4 << 2) + t; i < be; i += PB) {
            int d = dst[i];
            int b = d >> BSHIFT;
            int pos = atomicAdd(&lcur[b], 1);
            spack[pos] = ((unsigned int)src[i] << BSHIFT) | (unsigned int)(d & (BSZ - 1));
            sbkt[pos] = (unsigned short)b;
        }
        __syncthreads();
        // flush: per-bucket contiguous segments; nt stores (write-once stream)
        for (int j = t; j < cnt; j += PB) {
            unsigned int w = spack[j];
            int b = sbkt[j];
            int gi = gcur[b] + (j - loff[b]);
            if (IV) {
                float vv = g1[w >> BSHIFT];     // cached gather (g1 is 4 MB, L2-hot)
                uint32x2 o;
                o[0] = w;
                o[1] = __float_as_uint(vv);
                __builtin_nontemporal_store(o, bpack2 + gi);
            } else {
                __builtin_nontemporal_store(w, bpack + gi);
            }
        }
        __syncthreads();
        for (int b = t; b < NB; b += PB)
            gcur[b] += loff[b + 1] - loff[b];
        __syncthreads();
    }
}

// ---------------- v2 accumulate kernels ----------------

// A1v2: pure stream — {pack,val} records, no gather. Fused layer-1 MLP -> t.
__global__ void k_acc1v2(const uint32x2* __restrict__ bp, const int* __restrict__ base,
                         const float* __restrict__ norm,
                         const float* __restrict__ W1, const float* __restrict__ b1,
                         const float* __restrict__ W2,
                         float* __restrict__ t, int nN) {
    __shared__ float acc[BSZ];
    for (int j = threadIdx.x; j < BSZ; j += blockDim.x) acc[j] = 0.0f;
    __syncthreads();
    int b = blockIdx.x;
    int lo = base[b], hi = base[b + 1];
    int head = ((lo & 1) && lo < hi) ? 1 : 0;
    if (head && threadIdx.x == 0) {
        uint32x2 w = bp[lo];
        atomicAdd(&acc[w[0] & (BSZ - 1)], __uint_as_float(w[1]));
    }
    int lo2 = lo + head;
    int n2 = (hi - lo2) >> 1;                      // 16B records (2 edges)
    const uint32x4* p4 = (const uint32x4*)(bp + lo2);
    int i = threadIdx.x, bd = blockDim.x;
    for (; i + bd < n2; i += 2 * bd) {
        uint32x4 a = __builtin_nontemporal_load(p4 + i);
        uint32x4 c = __builtin_nontemporal_load(p4 + i + bd);
        atomicAdd(&acc[a[0] & (BSZ - 1)], __uint_as_float(a[1]));
        atomicAdd(&acc[a[2] & (BSZ - 1)], __uint_as_float(a[3]));
        atomicAdd(&acc[c[0] & (BSZ - 1)], __uint_as_float(c[1]));
        atomicAdd(&acc[c[2] & (BSZ - 1)], __uint_as_float(c[3]));
    }
    for (; i < n2; i += bd) {
        uint32x4 a = __builtin_nontemporal_load(p4 + i);
        atomicAdd(&acc[a[0] & (BSZ - 1)], __uint_as_float(a[1]));
        atomicAdd(&acc[a[2] & (BSZ - 1)], __uint_as_float(a[3]));
    }
    for (int j = lo2 + (n2 << 1) + (int)threadIdx.x; j < hi; j += bd) {
        uint32x2 w = bp[j];
        atomicAdd(&acc[w[0] & (BSZ - 1)], __uint_as_float(w[1]));
    }
    __syncthreads();
    float w10 = W1[0], w11 = W1[1], w12 = W1[2];
    float b10 = b1[0], b11 = b1[1], b12 = b1[2];
    float w20 = W2[0], w21 = W2[1], w22 = W2[2];
    int node0 = b << BSHIFT;
    for (int j = threadIdx.x; j < BSZ && node0 + j < nN; j += blockDim.x) {
        float nv = norm[node0 + j];
        float s = acc[j] * nv;
        float h0 = fmaxf(fmaf(s, w10, b10), 0.0f);
        float h1 = fmaxf(fmaf(s, w11, b11), 0.0f);
        float h2 = fmaxf(fmaf(s, w12, b12), 0.0f);
        t[node0 + j] = nv * (h0 * w20 + h1 * w21 + h2 * w22);
    }
}

// A2v2: stream records (nt, keeps L2 for t), gather t[src], fused relu -> out.
__global__ void k_acc2v2(const uint32x2* __restrict__ bp, const int* __restrict__ base,
                         const float* __restrict__ val, const float* __restrict__ norm,
                         const float* __restrict__ b2,
                         float* __restrict__ out, int nN) {
    __shared__ float acc[BSZ];
    for (int j = threadIdx.x; j < BSZ; j += blockDim.x) acc[j] = 0.0f;
    __syncthreads();
    int b = blockIdx.x;
    int lo = base[b], hi = base[b + 1];
    int head = ((lo & 1) && lo < hi) ? 1 : 0;
    if (head && threadIdx.x == 0) {
        uint32x2 w = bp[lo];
        atomicAdd(&acc[w[0] & (BSZ - 1)], val[w[0] >> BSHIFT]);
    }
    int lo2 = lo + head;
    int n2 = (hi - lo2) >> 1;
    const uint32x4* p4 = (const uint32x4*)(bp + lo2);
    int i = threadIdx.x, bd = blockDim.x;
    for (; i + bd < n2; i += 2 * bd) {
        uint32x4 a = __builtin_nontemporal_load(p4 + i);
        uint32x4 c = __builtin_nontemporal_load(p4 + i + bd);
        float v0 = val[a[0] >> BSHIFT];
        float v1 = val[a[2] >> BSHIFT];
        float v2 = val[c[0] >> BSHIFT];
        float v3 = val[c[2] >> BSHIFT];
        atomicAdd(&acc[a[0] & (BSZ - 1)], v0);
        atomicAdd(&acc[a[2] & (BSZ - 1)], v1);
        atomicAdd(&acc[c[0] & (BSZ - 1)], v2);
        atomicAdd(&acc[c[2] & (BSZ - 1)], v3);
    }
    for (; i < n2; i += bd) {
        uint32x4 a = __builtin_nontemporal_load(p4 + i);
        atomicAdd(&acc[a[0] & (BSZ - 1)], val[a[0] >> BSHIFT]);
        atomicAdd(&acc[a[2] & (BSZ - 1)], val[a[2] >> BSHIFT]);
    }
    for (int j = lo2 + (n2 << 1) + (int)threadIdx.x; j < hi; j += bd) {
        uint32x2 w = bp[j];
        atomicAdd(&acc[w[0] & (BSZ - 1)], val[w[0] >> BSHIFT]);
    }
    __syncthreads();
    float bb = b2[0];
    int node0 = b << BSHIFT;
    for (int j = threadIdx.x; j < BSZ && node0 + j < nN; j += blockDim.x)
        out[node0 + j] = fmaxf(acc[j] * norm[node0 + j] + bb, 0.0f);
}

// ---------------- v1 accumulate (gather both passes; used if ws is tight) ----

__device__ __forceinline__ void acc_body(const unsigned int* __restrict__ bpack,
                                         int lo, int hi,
                                         const float* __restrict__ val,
                                         float* acc) {
    int head = min((4 - (lo & 3)) & 3, hi - lo);
    for (int i = lo + (int)threadIdx.x; i < lo + head; i += blockDim.x) {
        unsigned int w = bpack[i];
        atomicAdd(&acc[w & (BSZ - 1)], val[w >> BSHIFT]);
    }
    int lo4 = lo + head;
    int n4 = (hi - lo4) >> 2;
    const uint32x4* p4 = (const uint32x4*)(bpack + lo4);
    int i = threadIdx.x;
    int bd = blockDim.x;
    for (; i + bd < n4; i += 2 * bd) {
        uint32x4 wa = __builtin_nontemporal_load(p4 + i);
        uint32x4 wb = __builtin_nontemporal_load(p4 + i + bd);
        float va0 = val[wa[0] >> BSHIFT], va1 = val[wa[1] >> BSHIFT];
        float va2 = val[wa[2] >> BSHIFT], va3 = val[wa[3] >> BSHIFT];
        float vb0 = val[wb[0] >> BSHIFT], vb1 = val[wb[1] >> BSHIFT];
        float vb2 = val[wb[2] >> BSHIFT], vb3 = val[wb[3] >> BSHIFT];
        atomicAdd(&acc[wa[0] & (BSZ - 1)], va0);
        atomicAdd(&acc[wa[1] & (BSZ - 1)], va1);
        atomicAdd(&acc[wa[2] & (BSZ - 1)], va2);
        atomicAdd(&acc[wa[3] & (BSZ - 1)], va3);
        atomicAdd(&acc[wb[0] & (BSZ - 1)], vb0);
        atomicAdd(&acc[wb[1] & (BSZ - 1)], vb1);
        atomicAdd(&acc[wb[2] & (BSZ - 1)], vb2);
        atomicAdd(&acc[wb[3] & (BSZ - 1)], vb3);
    }
    for (; i < n4; i += bd) {
        uint32x4 w = __builtin_nontemporal_load(p4 + i);
        atomicAdd(&acc[w[0] & (BSZ - 1)], val[w[0] >> BSHIFT]);
        atomicAdd(&acc[w[1] & (BSZ - 1)], val[w[1] >> BSHIFT]);
        atomicAdd(&acc[w[2] & (BSZ - 1)], val[w[2] >> BSHIFT]);
        atomicAdd(&acc[w[3] & (BSZ - 1)], val[w[3] >> BSHIFT]);
    }
    for (int j = lo4 + (n4 << 2) + (int)threadIdx.x; j < hi; j += blockDim.x) {
        unsigned int w = bpack[j];
        atomicAdd(&acc[w & (BSZ - 1)], val[w >> BSHIFT]);
    }
}

__global__ void k_acc1(const unsigned int* __restrict__ bpack,
                       const int* __restrict__ base,
                       const float* __restrict__ val, const float* __restrict__ norm,
                       const float* __restrict__ W1, const float* __restrict__ b1,
                       const float* __restrict__ W2,
                       float* __restrict__ t, int nN) {
    __shared__ float acc[BSZ];
    for (int j = threadIdx.x; j < BSZ; j += blockDim.x) acc[j] = 0.0f;
    __syncthreads();
    int b = blockIdx.x;
    acc_body(bpack, base[b], base[b + 1], val, acc);
    __syncthreads();
    float w10 = W1[0], w11 = W1[1], w12 = W1[2];
    float b10 = b1[0], b11 = b1[1], b12 = b1[2];
    float w20 = W2[0], w21 = W2[1], w22 = W2[2];
    int node0 = b << BSHIFT;
    for (int j = threadIdx.x; j < BSZ && node0 + j < nN; j += blockDim.x) {
        float nv = norm[node0 + j];
        float s = acc[j] * nv;
        float h0 = fmaxf(fmaf(s, w10, b10), 0.0f);
        float h1 = fmaxf(fmaf(s, w11, b11), 0.0f);
        float h2 = fmaxf(fmaf(s, w12, b12), 0.0f);
        t[node0 + j] = nv * (h0 * w20 + h1 * w21 + h2 * w22);
    }
}

__global__ void k_acc2(const unsigned int* __restrict__ bpack,
                       const int* __restrict__ base,
                       const float* __restrict__ val, const float* __restrict__ norm,
                       const float* __restrict__ b2,
                       float* __restrict__ out, int nN) {
    __shared__ float acc[BSZ];
    for (int j = threadIdx.x; j < BSZ; j += blockDim.x) acc[j] = 0.0f;
    __syncthreads();
    int b = blockIdx.x;
    acc_body(bpack, base[b], base[b + 1], val, acc);
    __syncthreads();
    float bb = b2[0];
    int node0 = b << BSHIFT;
    for (int j = threadIdx.x; j < BSZ && node0 + j < nN; j += blockDim.x)
        out[node0 + j] = fmaxf(acc[j] * norm[node0 + j] + bb, 0.0f);
}

// ---------------- fallback: direct device-scope atomic scatter ----------------
__global__ void k_edge_scatter(const int* __restrict__ src, const int* __restrict__ dst,
                               const float* __restrict__ val, float* __restrict__ agg,
                               int nE) {
    int stride = gridDim.x * blockDim.x;
    for (int e = blockIdx.x * blockDim.x + threadIdx.x; e < nE; e += stride)
        atomicAdd(&agg[dst[e]], val[src[e]]);
}

static inline size_t align256(size_t x) { return (x + 255) & ~(size_t)255; }

extern "C" void kernel_launch(void* const* d_in, const int* in_sizes, int n_in,
                              void* d_out, int out_size, void* d_ws, size_t ws_size,
                              hipStream_t stream) {
    const float* feat = (const float*)d_in[0];
    const float* norm = (const float*)d_in[1];
    const int*   src  = (const int*)d_in[2];
    const int*   dst  = (const int*)d_in[3];
    const float* W1   = (const float*)d_in[4];
    const float* b1   = (const float*)d_in[5];
    const float* W2   = (const float*)d_in[6];
    const float* b2   = (const float*)d_in[7];
    float* out = (float*)d_out;

    int nN = in_sizes[0];
    int nE = in_sizes[2];
    int NB = (nN + BSZ - 1) >> BSHIFT;

    // workspace layout (common prefix, then bpack2 [v2] or bpack [v1])
    char* p = (char*)d_ws;
    size_t off = 0;
    float* g1 = (float*)(p + off); off = align256(off + (size_t)nN * 4);
    float* t1 = (float*)(p + off); off = align256(off + (size_t)nN * 4);
    int* base     = (int*)(p + off); off = align256(off + (size_t)(NB + 1) * 4);
    int* tot      = (int*)(p + off); off = align256(off + (size_t)NB * 4);
    float* agg2   = (float*)(p + off);                        // fallback only
    int* counts   = (int*)(p + off); off = align256(off + (size_t)NB * NBIN_BLOCKS * 4);
    int* chunkpre = (int*)(p + off); off = align256(off + (size_t)NB * NBIN_BLOCKS * 4);
    size_t off_common = off;
    uint32x2* bpack2 = (uint32x2*)(p + off_common);
    unsigned int* bpack = (unsigned int*)(p + off_common);
    size_t need2 = align256(off_common + (size_t)nE * 8);
    size_t need1 = align256(off_common + (size_t)nE * 4);

    const int BLK = 256;
    int nodeBlocks = (nN + BLK - 1) / BLK;
    if (nodeBlocks > 2048) nodeBlocks = 2048;

    bool packed_ok = ((size_t)nN <= ((size_t)1 << (32 - BSHIFT))) && (NB <= NBMAX);
    if (packed_ok && ws_size >= need1) {
        int chunk = (nE + NBIN_BLOCKS - 1) / NBIN_BLOCKS;
        chunk = (chunk + 3) & ~3;                  // int4-aligned chunks
        size_t ldsNB = (size_t)NB * 4;
        bool v2 = (ws_size >= need2);

        k1b<<<nodeBlocks, BLK, 0, stream>>>(feat, norm, g1, nN);
        k_hist<<<NBIN_BLOCKS, 512, ldsNB, stream>>>(dst, nE, NB, chunk, counts);
        k_bucketscan<<<NB, 256, 0, stream>>>(counts, chunkpre, tot);
        k_exscan<<<1, 1024, 0, stream>>>(tot, NB, base);
        if (v2) {
            k_place2x<true><<<NBIN_BLOCKS, PB, 0, stream>>>(src, dst, g1, nE, NB, chunk,
                                                            chunkpre, base, nullptr, bpack2);
            k_acc1v2<<<NB, 512, 0, stream>>>(bpack2, base, norm, W1, b1, W2, t1, nN);
            k_acc2v2<<<NB, 512, 0, stream>>>(bpack2, base, t1, norm, b2, out, nN);
        } else {
            k_place2x<false><<<NBIN_BLOCKS, PB, 0, stream>>>(src, dst, g1, nE, NB, chunk,
                                                             chunkpre, base, bpack, nullptr);
            k_acc1<<<NB, 512, 0, stream>>>(bpack, base, g1, norm, W1, b1, W2, t1, nN);
            k_acc2<<<NB, 512, 0, stream>>>(bpack, base, t1, norm, b2, out, nN);
        }
    } else {
        // fallback: direct atomic scatter (round-1 path)
        int edgeBlocks = 2048;
        k1_prep<<<nodeBlocks, BLK, 0, stream>>>(feat, norm, g1, t1, agg2, nN);
        k_edge_scatter<<<edgeBlocks, BLK, 0, stream>>>(src, dst, g1, t1, nE);
        k3_mid<<<nodeBlocks, BLK, 0, stream>>>(t1, norm, W1, b1, W2, g1, nN);
        k_edge_scatter<<<edgeBlocks, BLK, 0, stream>>>(src, dst, g1, agg2, nE);
        k5_out<<<nodeBlocks, BLK, 0, stream>>>(agg2, norm, b2, out, nN);
    }
}

// Round 10
// 270.415 us; speedup vs baseline: 1.2998x; 1.2998x over previous
//
#include <hip/hip_runtime.h>

#define BSHIFT 11
#define BSZ (1 << BSHIFT)          // 2048 nodes per bucket
#define NBMAX 512
#define NBIN_BLOCKS 1024           // histogram/placement chunks
#define PB 512                     // k_place2 threads
#define BATCH 8192                 // edges sorted per LDS batch

typedef unsigned int uint32x4 __attribute__((ext_vector_type(4)));

// ---------------- node-map kernels ----------------

__global__ void k1b(const float* __restrict__ feat, const float* __restrict__ norm,
                    float* __restrict__ g1, int n) {
    int stride = gridDim.x * blockDim.x;
    for (int i = blockIdx.x * blockDim.x + threadIdx.x; i < n; i += stride)
        g1[i] = feat[i] * norm[i];
}

// fallback path helpers
__global__ void k1_prep(const float* __restrict__ feat, const float* __restrict__ norm,
                        float* __restrict__ g1, float* __restrict__ agg1,
                        float* __restrict__ agg2, int n) {
    int stride = gridDim.x * blockDim.x;
    for (int i = blockIdx.x * blockDim.x + threadIdx.x; i < n; i += stride) {
        g1[i] = feat[i] * norm[i];
        agg1[i] = 0.0f;
        agg2[i] = 0.0f;
    }
}

__global__ void k3_mid(const float* __restrict__ agg1, const float* __restrict__ norm,
                       const float* __restrict__ W1, const float* __restrict__ b1,
                       const float* __restrict__ W2, float* __restrict__ t, int n) {
    float w10 = W1[0], w11 = W1[1], w12 = W1[2];
    float b10 = b1[0], b11 = b1[1], b12 = b1[2];
    float w20 = W2[0], w21 = W2[1], w22 = W2[2];
    int stride = gridDim.x * blockDim.x;
    for (int i = blockIdx.x * blockDim.x + threadIdx.x; i < n; i += stride) {
        float nv = norm[i];
        float s = agg1[i] * nv;
        float h0 = fmaxf(fmaf(s, w10, b10), 0.0f);
        float h1 = fmaxf(fmaf(s, w11, b11), 0.0f);
        float h2 = fmaxf(fmaf(s, w12, b12), 0.0f);
        t[i] = nv * (h0 * w20 + h1 * w21 + h2 * w22);
    }
}

__global__ void k5_out(const float* __restrict__ agg2, const float* __restrict__ norm,
                       const float* __restrict__ b2, float* __restrict__ out, int n) {
    float b = b2[0];
    int stride = gridDim.x * blockDim.x;
    for (int i = blockIdx.x * blockDim.x + threadIdx.x; i < n; i += stride)
        out[i] = fmaxf(agg2[i] * norm[i] + b, 0.0f);
}

// ---------------- binning pipeline ----------------

// H: per-chunk LDS histogram -> counts[b * NBIN_BLOCKS + chunk]  (transposed)
__global__ void k_hist(const int* __restrict__ dst, int nE, int NB, int chunk,
                       int* __restrict__ counts) {
    extern __shared__ int lhist[];
    int t = threadIdx.x;
    for (int b = t; b < NB; b += blockDim.x) lhist[b] = 0;
    __syncthreads();
    int lo = blockIdx.x * chunk;
    int hi = min(lo + chunk, nE);
    int n4 = (hi - lo) >> 2;                       // lo % 4 == 0 (chunk % 4 == 0)
    const int4* d4 = (const int4*)(dst + lo);
    for (int i = t; i < n4; i += blockDim.x) {
        int4 v = d4[i];
        atomicAdd(&lhist[v.x >> BSHIFT], 1);
        atomicAdd(&lhist[v.y >> BSHIFT], 1);
        atomicAdd(&lhist[v.z >> BSHIFT], 1);
        atomicAdd(&lhist[v.w >> BSHIFT], 1);
    }
    for (int i = lo + (n4 << 2) + t; i < hi; i += blockDim.x)
        atomicAdd(&lhist[dst[i] >> BSHIFT], 1);
    __syncthreads();
    for (int b = t; b < NB; b += blockDim.x)
        counts[(size_t)b * NBIN_BLOCKS + blockIdx.x] = lhist[b];
}

// S1: one block per bucket — exclusive scan of its 1024 chunk counts.
__global__ void k_bucketscan(const int* __restrict__ counts,
                             int* __restrict__ chunkpre, int* __restrict__ tot) {
    __shared__ int ssum[256];
    int b = blockIdx.x;
    int t = threadIdx.x;
    const int4* in4 = (const int4*)(counts + (size_t)b * NBIN_BLOCKS);
    int4 v = in4[t];
    int mysum = v.x + v.y + v.z + v.w;
    ssum[t] = mysum;
    __syncthreads();
    for (int ofs = 1; ofs < 256; ofs <<= 1) {
        int add = (t >= ofs) ? ssum[t - ofs] : 0;
        __syncthreads();
        ssum[t] += add;
        __syncthreads();
    }
    int excl = ssum[t] - mysum;
    int4 o;
    o.x = excl;
    o.y = excl + v.x;
    o.z = o.y + v.y;
    o.w = o.z + v.z;
    ((int4*)(chunkpre + (size_t)b * NBIN_BLOCKS))[t] = o;
    if (t == 255) tot[b] = ssum[255];
}

// S2: exclusive scan over NB bucket totals -> base[0..NB]
__global__ void k_exscan(const int* __restrict__ tot, int NB, int* __restrict__ base) {
    __shared__ int s[1024];
    int t = threadIdx.x;
    if (NB < 1024) {
        int v = (t < NB) ? tot[t] : 0;
        s[t] = v;
        __syncthreads();
        for (int ofs = 1; ofs < 1024; ofs <<= 1) {
            int add = (t >= ofs) ? s[t - ofs] : 0;
            __syncthreads();
            s[t] += add;
            __syncthreads();
        }
        if (t < NB) base[t] = s[t] - v;
        if (t == NB) base[NB] = s[NB - 1];
    } else if (t == 0) {
        int run = 0;
        for (int b = 0; b < NB; ++b) { base[b] = run; run += tot[b]; }
        base[NB] = run;
    }
}

// P2: LDS-sorted placement. Phase A loads src/dst int4s into REGISTERS while
// histogramming; phase B scatters from registers (no second global read).
// Flush uses cached stores (L2 write-combining for scattered 4B segments).
__global__ void __launch_bounds__(PB)
k_place2(const int* __restrict__ src, const int* __restrict__ dst,
         int nE, int NB, int chunk,
         const int* __restrict__ chunkpre, const int* __restrict__ base,
         unsigned int* __restrict__ bpack) {
    __shared__ unsigned int spack[BATCH];      // 32 KB sorted packed edges
    __shared__ unsigned short sbkt[BATCH];     // 16 KB bucket id per slot
    __shared__ int lcur[NBMAX];
    __shared__ int loff[NBMAX + 1];
    __shared__ int gcur[NBMAX];
    __shared__ int ssc[NBMAX];
    int t = threadIdx.x;
    int blk = blockIdx.x;

    for (int b = t; b < NB; b += PB)
        gcur[b] = base[b] + chunkpre[(size_t)b * NBIN_BLOCKS + blk];

    int lo = blk * chunk;
    int hi = min(lo + chunk, nE);
    for (int bs = lo; bs < hi; bs += BATCH) {
        int be = min(bs + BATCH, hi);
        int cnt = be - bs;
        lcur[t] = 0;
        __syncthreads();
        // phase A: histogram + hold src/dst int4s in registers
        int n4 = cnt >> 2;                         // bs % 4 == 0
        const int4* d4 = (const int4*)(dst + bs);
        const int4* s4 = (const int4*)(src + bs);
        int4 dvs[4], svs[4];                       // static-indexed (unrolled)
        #pragma unroll
        for (int u = 0; u < 4; ++u) {
            int i = t + u * PB;
            if (i < n4) {
                int4 dv = d4[i];
                int4 sv = s4[i];
                dvs[u] = dv; svs[u] = sv;
                atomicAdd(&lcur[dv.x >> BSHIFT], 1);
                atomicAdd(&lcur[dv.y >> BSHIFT], 1);
                atomicAdd(&lcur[dv.z >> BSHIFT], 1);
                atomicAdd(&lcur[dv.w >> BSHIFT], 1);
            }
        }
        for (int i = bs + (n4 << 2) + t; i < be; i += PB)
            atomicAdd(&lcur[dst[i] >> BSHIFT], 1);
        __syncthreads();
        // scan 512 (Hillis-Steele inclusive) -> exclusive offsets
        int v = lcur[t];
        ssc[t] = v;
        __syncthreads();
        for (int ofs = 1; ofs < 512; ofs <<= 1) {
            int add = (t >= ofs) ? ssc[t - ofs] : 0;
            __syncthreads();
            ssc[t] += add;
            __syncthreads();
        }
        int excl = ssc[t] - v;
        loff[t] = excl;
        lcur[t] = excl;
        if (t == 511) loff[512] = ssc[511];
        __syncthreads();
        // phase B: sorted scatter into LDS from registers
        #pragma unroll
        for (int u = 0; u < 4; ++u) {
            int i = t + u * PB;
            if (i < n4) {
                int4 dv = dvs[u];
                int4 sv = svs[u];
                int b0 = dv.x >> BSHIFT, p0 = atomicAdd(&lcur[b0], 1);
                spack[p0] = ((unsigned int)sv.x << BSHIFT) | (unsigned int)(dv.x & (BSZ - 1));
                sbkt[p0] = (unsigned short)b0;
                int b1 = dv.y >> BSHIFT, p1 = atomicAdd(&lcur[b1], 1);
                spack[p1] = ((unsigned int)sv.y << BSHIFT) | (unsigned int)(dv.y & (BSZ - 1));
                sbkt[p1] = (unsigned short)b1;
                int b2 = dv.z >> BSHIFT, p2 = atomicAdd(&lcur[b2], 1);
                spack[p2] = ((unsigned int)sv.z << BSHIFT) | (unsigned int)(dv.z & (BSZ - 1));
                sbkt[p2] = (unsigned short)b2;
                int b3 = dv.w >> BSHIFT, p3 = atomicAdd(&lcur[b3], 1);
                spack[p3] = ((unsigned int)sv.w << BSHIFT) | (unsigned int)(dv.w & (BSZ - 1));
                sbkt[p3] = (unsigned short)b3;
            }
        }
        for (int i = bs + (n4 << 2) + t; i < be; i += PB) {
            int d = dst[i];
            int b = d >> BSHIFT;
            int pos = atomicAdd(&lcur[b], 1);
            spack[pos] = ((unsigned int)src[i] << BSHIFT) | (unsigned int)(d & (BSZ - 1));
            sbkt[pos] = (unsigned short)b;
        }
        __syncthreads();
        // flush: per-bucket contiguous segments, cached stores
        for (int j = t; j < cnt; j += PB) {
            int b = sbkt[j];
            bpack[gcur[b] + (j - loff[b])] = spack[j];
        }
        __syncthreads();
        for (int b = t; b < NB; b += PB)
            gcur[b] += loff[b + 1] - loff[b];
        __syncthreads();
    }
}

// shared accumulate body: nt-stream bpack (2x uint4 unroll = 8 gathers in flight)
__device__ __forceinline__ void acc_body(const unsigned int* __restrict__ bpack,
                                         int lo, int hi,
                                         const float* __restrict__ val,
                                         float* acc) {
    int head = min((4 - (lo & 3)) & 3, hi - lo);
    for (int i = lo + (int)threadIdx.x; i < lo + head; i += blockDim.x) {
        unsigned int w = bpack[i];
        atomicAdd(&acc[w & (BSZ - 1)], val[w >> BSHIFT]);
    }
    int lo4 = lo + head;
    int n4 = (hi - lo4) >> 2;
    const uint32x4* p4 = (const uint32x4*)(bpack + lo4);
    int i = threadIdx.x;
    int bd = blockDim.x;
    for (; i + bd < n4; i += 2 * bd) {
        uint32x4 wa = __builtin_nontemporal_load(p4 + i);
        uint32x4 wb = __builtin_nontemporal_load(p4 + i + bd);
        float va0 = val[wa[0] >> BSHIFT], va1 = val[wa[1] >> BSHIFT];
        float va2 = val[wa[2] >> BSHIFT], va3 = val[wa[3] >> BSHIFT];
        float vb0 = val[wb[0] >> BSHIFT], vb1 = val[wb[1] >> BSHIFT];
        float vb2 = val[wb[2] >> BSHIFT], vb3 = val[wb[3] >> BSHIFT];
        atomicAdd(&acc[wa[0] & (BSZ - 1)], va0);
        atomicAdd(&acc[wa[1] & (BSZ - 1)], va1);
        atomicAdd(&acc[wa[2] & (BSZ - 1)], va2);
        atomicAdd(&acc[wa[3] & (BSZ - 1)], va3);
        atomicAdd(&acc[wb[0] & (BSZ - 1)], vb0);
        atomicAdd(&acc[wb[1] & (BSZ - 1)], vb1);
        atomicAdd(&acc[wb[2] & (BSZ - 1)], vb2);
        atomicAdd(&acc[wb[3] & (BSZ - 1)], vb3);
    }
    for (; i < n4; i += bd) {
        uint32x4 w = __builtin_nontemporal_load(p4 + i);
        atomicAdd(&acc[w[0] & (BSZ - 1)], val[w[0] >> BSHIFT]);
        atomicAdd(&acc[w[1] & (BSZ - 1)], val[w[1] >> BSHIFT]);
        atomicAdd(&acc[w[2] & (BSZ - 1)], val[w[2] >> BSHIFT]);
        atomicAdd(&acc[w[3] & (BSZ - 1)], val[w[3] >> BSHIFT]);
    }
    for (int j = lo4 + (n4 << 2) + (int)threadIdx.x; j < hi; j += blockDim.x) {
        unsigned int w = bpack[j];
        atomicAdd(&acc[w & (BSZ - 1)], val[w >> BSHIFT]);
    }
}

// A1: bucket accumulate of g1 + fused layer-1 MLP -> t[node]
__global__ void k_acc1(const unsigned int* __restrict__ bpack,
                       const int* __restrict__ base,
                       const float* __restrict__ val, const float* __restrict__ norm,
                       const float* __restrict__ W1, const float* __restrict__ b1,
                       const float* __restrict__ W2,
                       float* __restrict__ t, int nN) {
    __shared__ float acc[BSZ];
    for (int j = threadIdx.x; j < BSZ; j += blockDim.x) acc[j] = 0.0f;
    __syncthreads();
    int b = blockIdx.x;
    acc_body(bpack, base[b], base[b + 1], val, acc);
    __syncthreads();
    float w10 = W1[0], w11 = W1[1], w12 = W1[2];
    float b10 = b1[0], b11 = b1[1], b12 = b1[2];
    float w20 = W2[0], w21 = W2[1], w22 = W2[2];
    int node0 = b << BSHIFT;
    for (int j = threadIdx.x; j < BSZ && node0 + j < nN; j += blockDim.x) {
        float nv = norm[node0 + j];
        float s = acc[j] * nv;
        float h0 = fmaxf(fmaf(s, w10, b10), 0.0f);
        float h1 = fmaxf(fmaf(s, w11, b11), 0.0f);
        float h2 = fmaxf(fmaf(s, w12, b12), 0.0f);
        t[node0 + j] = nv * (h0 * w20 + h1 * w21 + h2 * w22);
    }
}

// A2: bucket accumulate of t + fused output relu -> out[node]
__global__ void k_acc2(const unsigned int* __restrict__ bpack,
                       const int* __restrict__ base,
                       const float* __restrict__ val, const float* __restrict__ norm,
                       const float* __restrict__ b2,
                       float* __restrict__ out, int nN) {
    __shared__ float acc[BSZ];
    for (int j = threadIdx.x; j < BSZ; j += blockDim.x) acc[j] = 0.0f;
    __syncthreads();
    int b = blockIdx.x;
    acc_body(bpack, base[b], base[b + 1], val, acc);
    __syncthreads();
    float bb = b2[0];
    int node0 = b << BSHIFT;
    for (int j = threadIdx.x; j < BSZ && node0 + j < nN; j += blockDim.x)
        out[node0 + j] = fmaxf(acc[j] * norm[node0 + j] + bb, 0.0f);
}

// ---------------- fallback: direct device-scope atomic scatter ----------------
__global__ void k_edge_scatter(const int* __restrict__ src, const int* __restrict__ dst,
                               const float* __restrict__ val, float* __restrict__ agg,
                               int nE) {
    int stride = gridDim.x * blockDim.x;
    for (int e = blockIdx.x * blockDim.x + threadIdx.x; e < nE; e += stride)
        atomicAdd(&agg[dst[e]], val[src[e]]);
}

static inline size_t align256(size_t x) { return (x + 255) & ~(size_t)255; }

extern "C" void kernel_launch(void* const* d_in, const int* in_sizes, int n_in,
                              void* d_out, int out_size, void* d_ws, size_t ws_size,
                              hipStream_t stream) {
    const float* feat = (const float*)d_in[0];
    const float* norm = (const float*)d_in[1];
    const int*   src  = (const int*)d_in[2];
    const int*   dst  = (const int*)d_in[3];
    const float* W1   = (const float*)d_in[4];
    const float* b1   = (const float*)d_in[5];
    const float* W2   = (const float*)d_in[6];
    const float* b2   = (const float*)d_in[7];
    float* out = (float*)d_out;

    int nN = in_sizes[0];
    int nE = in_sizes[2];
    int NB = (nN + BSZ - 1) >> BSHIFT;

    // workspace layout
    char* p = (char*)d_ws;
    size_t off = 0;
    float* g1 = (float*)(p + off); off = align256(off + (size_t)nN * 4);
    float* t1 = (float*)(p + off); off = align256(off + (size_t)nN * 4);
    int* base     = (int*)(p + off); off = align256(off + (size_t)(NB + 1) * 4);
    int* tot      = (int*)(p + off); off = align256(off + (size_t)NB * 4);
    float* agg2   = (float*)(p + off);                        // fallback only
    int* counts   = (int*)(p + off); off = align256(off + (size_t)NB * NBIN_BLOCKS * 4);
    int* chunkpre = (int*)(p + off); off = align256(off + (size_t)NB * NBIN_BLOCKS * 4);
    unsigned int* bpack = (unsigned int*)(p + off); off = align256(off + (size_t)nE * 4);
    size_t need = off;

    const int BLK = 256;
    int nodeBlocks = (nN + BLK - 1) / BLK;
    if (nodeBlocks > 2048) nodeBlocks = 2048;

    bool packed_ok = ((size_t)nN <= ((size_t)1 << (32 - BSHIFT))) && (NB <= NBMAX);
    if (packed_ok && ws_size >= need) {
        int chunk = (nE + NBIN_BLOCKS - 1) / NBIN_BLOCKS;
        chunk = (chunk + 3) & ~3;                  // int4-aligned chunks
        size_t ldsNB = (size_t)NB * 4;

        k1b<<<nodeBlocks, BLK, 0, stream>>>(feat, norm, g1, nN);
        k_hist<<<NBIN_BLOCKS, 512, ldsNB, stream>>>(dst, nE, NB, chunk, counts);
        k_bucketscan<<<NB, 256, 0, stream>>>(counts, chunkpre, tot);
        k_exscan<<<1, 1024, 0, stream>>>(tot, NB, base);
        k_place2<<<NBIN_BLOCKS, PB, 0, stream>>>(src, dst, nE, NB, chunk,
                                                 chunkpre, base, bpack);
        k_acc1<<<NB, 512, 0, stream>>>(bpack, base, g1, norm, W1, b1, W2, t1, nN);
        k_acc2<<<NB, 512, 0, stream>>>(bpack, base, t1, norm, b2, out, nN);
    } else {
        // fallback: direct atomic scatter (round-1 path)
        int edgeBlocks = 2048;
        k1_prep<<<nodeBlocks, BLK, 0, stream>>>(feat, norm, g1, t1, agg2, nN);
        k_edge_scatter<<<edgeBlocks, BLK, 0, stream>>>(src, dst, g1, t1, nE);
        k3_mid<<<nodeBlocks, BLK, 0, stream>>>(t1, norm, W1, b1, W2, g1, nN);
        k_edge_scatter<<<edgeBlocks, BLK, 0, stream>>>(src, dst, g1, agg2, nE);
        k5_out<<<nodeBlocks, BLK, 0, stream>>>(agg2, norm, b2, out, nN);
    }
}